// Round 18
// baseline (124.342 us; speedup 1.0000x reference)
//
#include <hip/hip_runtime.h>
#include <cstddef>

// B=2048, N=64, C_IN=512, C_H=128, NUM_CLASSES=2, E=1024
#define NN   64
#define CIN  512
#define CH   128

typedef unsigned short ushort_t;
typedef __attribute__((ext_vector_type(8))) short bf16x8;
typedef __attribute__((ext_vector_type(4))) short bf16x4;
typedef __attribute__((ext_vector_type(4))) float f32x4;

__device__ __forceinline__ ushort_t f2bf(float f) {          // RN-even fp32->bf16
    union { float f; unsigned u; } v; v.f = f;
    unsigned r = v.u + 0x7fffu + ((v.u >> 16) & 1u);
    return (ushort_t)(r >> 16);
}
__device__ __forceinline__ float bf2f(ushort_t b) {
    union { unsigned u; float f; } v; v.u = ((unsigned)b) << 16;
    return v.f;
}

// ---------------------------------------------------------------------------
// Kernel 1: block 0 builds normalized adjacency A (hi/lo bf16); blocks 1..64
// transpose + bf16 W1 (hi only) and W2 (hi only).
// ---------------------------------------------------------------------------
__global__ __launch_bounds__(256) void prep_all(const int* __restrict__ ei, int E,
                                                const float* __restrict__ W1,
                                                const float* __restrict__ W2,
                                                ushort_t* __restrict__ Ah, ushort_t* __restrict__ Al,
                                                ushort_t* __restrict__ W1h,
                                                ushort_t* __restrict__ W2h) {
    const int t = threadIdx.x;
    if (blockIdx.x == 0) {
        __shared__ float sdeg[NN];
        __shared__ float snorm[NN];
        __shared__ float sA[NN * NN];
        if (t < NN) sdeg[t] = 0.f;
        for (int i = t; i < NN * NN; i += 256) sA[i] = 0.f;
        __syncthreads();
        for (int e = t; e < E; e += 256) atomicAdd(&sdeg[ei[E + e]], 1.0f);
        __syncthreads();
        if (t < NN) snorm[t] = rsqrtf(sdeg[t] + 1.0f);
        __syncthreads();
        for (int e = t; e < E; e += 256) {
            int s = ei[e], d = ei[E + e];
            atomicAdd(&sA[d * NN + s], snorm[s] * snorm[d]);
        }
        if (t < NN) atomicAdd(&sA[t * NN + t], snorm[t] * snorm[t]);
        __syncthreads();
        for (int i = t; i < NN * NN; i += 256) {
            float a = sA[i];
            ushort_t h = f2bf(a);
            Ah[i] = h;
            Al[i] = f2bf(a - bf2f(h));
        }
    } else {
        const int idx = (blockIdx.x - 1) * 256 + t;
        const int stride = 64 * 256;
        for (int i = idx; i < CIN * CH; i += stride) {
            int k = i / CH, c = i % CH;
            W1h[c * CIN + k] = f2bf(W1[i]);          // hi only
        }
        for (int i = idx; i < CH * CH; i += stride) {
            int k = i / CH, c = i % CH;
            W2h[c * CH + k] = f2bf(W2[i]);           // hi only
        }
    }
}

// issue X loads for global chunk KC into named register set XR
#define ISSUE_X(XR, KC)                                                       \
{                                                                             \
    _Pragma("unroll")                                                         \
    for (int rf = 0; rf < 2; ++rf) {                                          \
        const float* xp = xp0 + rf * 16 * CIN + (KC) * 64;                    \
        XR[rf][0][0] = *reinterpret_cast<const float4*>(xp);                  \
        XR[rf][0][1] = *reinterpret_cast<const float4*>(xp + 4);              \
        XR[rf][1][0] = *reinterpret_cast<const float4*>(xp + 32);             \
        XR[rf][1][1] = *reinterpret_cast<const float4*>(xp + 36);             \
    }                                                                         \
}

// convert named set XR (loaded >= 1 phase ago) and MFMA against resident W
// at local chunk KCL (0..3 within the phase)
#define COMPUTE_CHUNK(XR, KCL)                                                \
{                                                                             \
    bf16x8 xh[2][2];                                                          \
    _Pragma("unroll")                                                         \
    for (int rf = 0; rf < 2; ++rf)                                            \
        _Pragma("unroll")                                                     \
        for (int ks = 0; ks < 2; ++ks) {                                      \
            const float xv[8] = {XR[rf][ks][0].x, XR[rf][ks][0].y,            \
                                 XR[rf][ks][0].z, XR[rf][ks][0].w,            \
                                 XR[rf][ks][1].x, XR[rf][ks][1].y,            \
                                 XR[rf][ks][1].z, XR[rf][ks][1].w};           \
            _Pragma("unroll")                                                 \
            for (int j = 0; j < 8; ++j)                                       \
                xh[rf][ks][j] = (short)f2bf(xv[j]);                           \
        }                                                                     \
    _Pragma("unroll")                                                         \
    for (int ks = 0; ks < 2; ++ks) {                                          \
        _Pragma("unroll")                                                     \
        for (int ct = 0; ct < 8; ++ct) {                                      \
            const int c = ct * 16 + lr;                                       \
            const int gk = (KCL) * 8 + (((ks << 2) | lk) ^ (c & 7));          \
            bf16x8 wh = *reinterpret_cast<const bf16x8*>(&lds[c * 256 + gk * 8]); \
            _Pragma("unroll")                                                 \
            for (int rf = 0; rf < 2; ++rf)                                    \
                acc[rf][ct] = __builtin_amdgcn_mfma_f32_16x16x32_bf16(xh[rf][ks], wh, acc[rf][ct], 0, 0, 0); \
        }                                                                     \
    }                                                                         \
}

// ---------------------------------------------------------------------------
// Kernel 2: FULLY FUSED — R18 = R17 + 4-DEEP X prefetch in the barrier-free
// phases. Prologue issues chunks 0-3 into xrA..xrD; each chunk's compute
// re-issues its set for chunk+4 (consumed next phase). Every X load is now
// issued a full phase (~1200+ cyc) before use and no drain flattens it
// (R12's 2-deep ran under 8 per-chunk drains; R17 was 1-deep).
// Structure otherwise identical to R17: 256 thr = 4 waves; wave w owns rows
// [w*32,+32) (rf=2x16) x 128 cols (ct=8); block = 2 batches; resident-W
// per K-half ([128c][256k] 64KB, staged once per phase); 1-pass X-hi gemm1;
// tail = agg1 (A 2-pass) -> gemm2 (W2h LDS, 1-pass) -> agg2 -> FC.
// LDS 64KB -> 2 blocks/CU. 16B-granule XOR swizzle everywhere (both-sides).
// ---------------------------------------------------------------------------
__global__ __launch_bounds__(256, 2) void fused_all(
    const float* __restrict__ x,
    const ushort_t* __restrict__ W1h,
    const ushort_t* __restrict__ Ah, const ushort_t* __restrict__ Al,
    const ushort_t* __restrict__ W2h,
    const float* __restrict__ b1, const float* __restrict__ b2,
    const float* __restrict__ fcW, const float* __restrict__ fcb,
    float* __restrict__ out)
{
    __shared__ ushort_t lds[32768];     // 65536 B
    __shared__ float sred[16];

    const int t   = threadIdx.x;
    const int l   = t & 63;
    const int w   = t >> 6;             // 0..3
    const int lr  = l & 15;
    const int lk  = l >> 4;
    const int lr7 = lr & 7;
    const size_t rbase = (size_t)blockIdx.x * 128;

    const float* xp0 = x + (rbase + w * 32 + lr) * CIN + lk * 8;
    float4 xrA[2][2][2], xrB[2][2][2], xrC[2][2][2], xrD[2][2][2];

    // ---- prologue: issue X chunks 0..3 (4-deep) ----
    ISSUE_X(xrA, 0);
    ISSUE_X(xrB, 1);
    ISSUE_X(xrC, 2);
    ISSUE_X(xrD, 3);

    f32x4 acc[2][8];
    #pragma unroll
    for (int rf = 0; rf < 2; ++rf)
        #pragma unroll
        for (int ct = 0; ct < 8; ++ct)
            #pragma unroll
            for (int i = 0; i < 4; ++i) acc[rf][ct][i] = 0.f;

    // ---- gemm1 phase 0: stage W K-half 0, compute chunks 0..3,
    //      re-issuing each set for chunks 4..7 ----
    #pragma unroll
    for (int u = 0; u < 16; ++u) {
        int idx = u * 256 + t;
        int c = idx >> 5, g = idx & 31;
        int gs = (g & ~7) | ((g & 7) ^ (c & 7));
        *reinterpret_cast<bf16x8*>(&lds[c * 256 + gs * 8]) =
            *reinterpret_cast<const bf16x8*>(W1h + (size_t)c * CIN + g * 8);
    }
    __syncthreads();

    COMPUTE_CHUNK(xrA, 0); ISSUE_X(xrA, 4);
    COMPUTE_CHUNK(xrB, 1); ISSUE_X(xrB, 5);
    COMPUTE_CHUNK(xrC, 2); ISSUE_X(xrC, 6);
    COMPUTE_CHUNK(xrD, 3); ISSUE_X(xrD, 7);

    // ---- gemm1 phase 1: stage W K-half 1, compute chunks 4..7 ----
    __syncthreads();
    #pragma unroll
    for (int u = 0; u < 16; ++u) {
        int idx = u * 256 + t;
        int c = idx >> 5, g = idx & 31;
        int gs = (g & ~7) | ((g & 7) ^ (c & 7));
        *reinterpret_cast<bf16x8*>(&lds[c * 256 + gs * 8]) =
            *reinterpret_cast<const bf16x8*>(W1h + (size_t)c * CIN + 256 + g * 8);
    }
    __syncthreads();

    COMPUTE_CHUNK(xrA, 0);
    COMPUTE_CHUNK(xrB, 1);
    COMPUTE_CHUNK(xrC, 2);
    COMPUTE_CHUNK(xrD, 3);

    __syncthreads();                    // gemm1 done; W region now dead

    // ================= tail (in-block) =================
    // sYt: batch qb at lds[qb*8192], tile [c(128)][n(64)] swizzled.
    // sH1: batch qb at lds[16384 + qb*8192], tile [n(64)][c(128)] swizzled.

    // ---- Y1 (registers) -> sYt, bf16 ----
    #pragma unroll
    for (int rf = 0; rf < 2; ++rf) {
        const int grow = w * 32 + rf * 16 + lk * 4;
        const int qb   = grow >> 6;
        const int n0   = grow & 63;
        const int gn   = n0 >> 3, noff = n0 & 7;
        #pragma unroll
        for (int ct = 0; ct < 8; ++ct) {
            const int c = ct * 16 + lr;
            bf16x4 yv;
            #pragma unroll
            for (int r = 0; r < 4; ++r) yv[r] = (short)f2bf(acc[rf][ct][r]);
            *reinterpret_cast<bf16x4*>(&lds[qb * 8192 + c * 64 + ((gn ^ lr7) << 3) + noff]) = yv;
        }
    }
    __syncthreads();

    const int q = w >> 1;               // batch within block
    const int h = w & 1;                // 32-row half
    ushort_t* sYtq = &lds[q * 8192];
    ushort_t* sH1q = &lds[16384 + q * 8192];

    // ---- agg1: H1 = relu(A @ Y1 + b1) -> sH1 ----
    bf16x8 ahf[2][2], alf[2][2];        // [rf][ks]
    #pragma unroll
    for (int rf = 0; rf < 2; ++rf)
        #pragma unroll
        for (int ks = 0; ks < 2; ++ks) {
            const int nrow = h * 32 + rf * 16 + lr;
            const int ko = ks * 32 + lk * 8;
            ahf[rf][ks] = *reinterpret_cast<const bf16x8*>(Ah + nrow * NN + ko);
            alf[rf][ks] = *reinterpret_cast<const bf16x8*>(Al + nrow * NN + ko);
        }
    {
        f32x4 hacc[2][8];
        #pragma unroll
        for (int rf = 0; rf < 2; ++rf)
            #pragma unroll
            for (int ct = 0; ct < 8; ++ct)
                #pragma unroll
                for (int i = 0; i < 4; ++i) hacc[rf][ct][i] = 0.f;
        #pragma unroll
        for (int ks = 0; ks < 2; ++ks) {
            const int swz = (((ks << 2) | lk) ^ lr7) << 3;
            #pragma unroll
            for (int ct = 0; ct < 8; ++ct) {
                const int c = ct * 16 + lr;
                bf16x8 y = *reinterpret_cast<const bf16x8*>(&sYtq[c * 64 + swz]);
                #pragma unroll
                for (int rf = 0; rf < 2; ++rf) {
                    hacc[rf][ct] = __builtin_amdgcn_mfma_f32_16x16x32_bf16(ahf[rf][ks], y, hacc[rf][ct], 0, 0, 0);
                    hacc[rf][ct] = __builtin_amdgcn_mfma_f32_16x16x32_bf16(alf[rf][ks], y, hacc[rf][ct], 0, 0, 0);
                }
            }
        }
        #pragma unroll
        for (int rf = 0; rf < 2; ++rf)
            #pragma unroll
            for (int ct = 0; ct < 8; ++ct) {
                const int c = ct * 16 + lr;
                const int gc = c >> 3;
                const float bias = b1[c];
                #pragma unroll
                for (int r = 0; r < 4; ++r) {
                    const int n = h * 32 + rf * 16 + lk * 4 + r;
                    float v = fmaxf(hacc[rf][ct][r] + bias, 0.f);
                    sH1q[n * 128 + ((gc ^ (n & 7)) << 3) + (c & 7)] = f2bf(v);
                }
            }
    }
    __syncthreads();

    // ---- stage W2h into LDS (sYt region; Y1 dead, Y2 not yet written) ----
    #pragma unroll
    for (int u = 0; u < 8; ++u) {
        int idx = u * 256 + t;          // granule id 0..2047
        int c = idx >> 4, g = idx & 15;
        *reinterpret_cast<bf16x8*>(&lds[c * 128 + ((g ^ (c & 7)) << 3)]) =
            *reinterpret_cast<const bf16x8*>(W2h + (size_t)c * CH + g * 8);
    }
    __syncthreads();

    // ---- gemm2: Y2 = H1 @ W2h (1-pass), W2 from LDS ----
    f32x4 acc2[2][8];
    #pragma unroll
    for (int rf = 0; rf < 2; ++rf)
        #pragma unroll
        for (int ct = 0; ct < 8; ++ct)
            #pragma unroll
            for (int i = 0; i < 4; ++i) acc2[rf][ct][i] = 0.f;
    {
        bf16x8 hf[2][4];                // [rf][ks], K=128
        #pragma unroll
        for (int rf = 0; rf < 2; ++rf) {
            const int n = h * 32 + rf * 16 + lr;
            #pragma unroll
            for (int ks = 0; ks < 4; ++ks) {
                const int gh = ((ks << 2) | lk) ^ (n & 7);
                hf[rf][ks] = *reinterpret_cast<const bf16x8*>(&sH1q[n * 128 + (gh << 3)]);
            }
        }
        #pragma unroll
        for (int ct = 0; ct < 8; ++ct) {
            const int c = ct * 16 + lr;
            #pragma unroll
            for (int ks = 0; ks < 4; ++ks) {
                const int gw = ((ks << 2) | lk) ^ (c & 7);
                bf16x8 w2 = *reinterpret_cast<const bf16x8*>(&lds[c * 128 + (gw << 3)]);
                #pragma unroll
                for (int rf = 0; rf < 2; ++rf)
                    acc2[rf][ct] = __builtin_amdgcn_mfma_f32_16x16x32_bf16(hf[rf][ks], w2, acc2[rf][ct], 0, 0, 0);
            }
        }
    }
    __syncthreads();                    // all W2h reads done before Y2 overwrite

    // Y2 -> sYt
    #pragma unroll
    for (int rf = 0; rf < 2; ++rf) {
        const int n0 = h * 32 + rf * 16 + lk * 4;
        const int gn = n0 >> 3, noff = n0 & 7;
        #pragma unroll
        for (int ct = 0; ct < 8; ++ct) {
            const int c = ct * 16 + lr;
            bf16x4 yv;
            #pragma unroll
            for (int r = 0; r < 4; ++r) yv[r] = (short)f2bf(acc2[rf][ct][r]);
            *reinterpret_cast<bf16x4*>(&sYtq[c * 64 + ((gn ^ lr7) << 3) + noff]) = yv;
        }
    }
    __syncthreads();

    // ---- agg2 + bias + relu + FC ----
    float p0 = 0.f, p1 = 0.f;
    {
        f32x4 h2[2][8];
        #pragma unroll
        for (int rf = 0; rf < 2; ++rf)
            #pragma unroll
            for (int ct = 0; ct < 8; ++ct)
                #pragma unroll
                for (int i = 0; i < 4; ++i) h2[rf][ct][i] = 0.f;
        #pragma unroll
        for (int ks = 0; ks < 2; ++ks) {
            const int swz = (((ks << 2) | lk) ^ lr7) << 3;
            #pragma unroll
            for (int ct = 0; ct < 8; ++ct) {
                const int c = ct * 16 + lr;
                bf16x8 y = *reinterpret_cast<const bf16x8*>(&sYtq[c * 64 + swz]);
                #pragma unroll
                for (int rf = 0; rf < 2; ++rf) {
                    h2[rf][ct] = __builtin_amdgcn_mfma_f32_16x16x32_bf16(ahf[rf][ks], y, h2[rf][ct], 0, 0, 0);
                    h2[rf][ct] = __builtin_amdgcn_mfma_f32_16x16x32_bf16(alf[rf][ks], y, h2[rf][ct], 0, 0, 0);
                }
            }
        }
        #pragma unroll
        for (int rf = 0; rf < 2; ++rf)
            #pragma unroll
            for (int ct = 0; ct < 8; ++ct) {
                const int c = ct * 16 + lr;
                const float bias = b2[c];
                #pragma unroll
                for (int r = 0; r < 4; ++r) {
                    const int n = h * 32 + rf * 16 + lk * 4 + r;
                    float v = fmaxf(h2[rf][ct][r] + bias, 0.f);
                    const float2 fw = *reinterpret_cast<const float2*>(fcW + ((size_t)(n * CH + c)) * 2);
                    p0 = fmaf(v, fw.x, p0);
                    p1 = fmaf(v, fw.y, p1);
                }
            }
    }
    #pragma unroll
    for (int off = 32; off > 0; off >>= 1) {
        p0 += __shfl_down(p0, off);
        p1 += __shfl_down(p1, off);
    }
    if (l == 0) { sred[w * 2] = p0; sred[w * 2 + 1] = p1; }
    __syncthreads();
    if (t == 0) {
        const size_t bA = (size_t)blockIdx.x * 2;
        out[bA * 2 + 0]       = sred[0] + sred[2] + fcb[0];
        out[bA * 2 + 1]       = sred[1] + sred[3] + fcb[1];
        out[(bA + 1) * 2 + 0] = sred[4] + sred[6] + fcb[0];
        out[(bA + 1) * 2 + 1] = sred[5] + sred[7] + fcb[1];
    }
}

// ---------------------------------------------------------------------------
extern "C" void kernel_launch(void* const* d_in, const int* in_sizes, int n_in,
                              void* d_out, int out_size, void* d_ws, size_t ws_size,
                              hipStream_t stream) {
    const float* x   = (const float*)d_in[0];
    const int*   ei  = (const int*)d_in[1];
    const float* W1  = (const float*)d_in[2];
    const float* b1  = (const float*)d_in[3];
    const float* W2  = (const float*)d_in[4];
    const float* b2  = (const float*)d_in[5];
    const float* fcW = (const float*)d_in[6];
    const float* fcb = (const float*)d_in[7];
    float* outp = (float*)d_out;

    // ws layout (bf16 elems): Ah,Al [64*64]; W1h [128*512]; W2h [128*128]
    ushort_t* Ah  = (ushort_t*)d_ws;
    ushort_t* Al  = Ah + NN * NN;
    ushort_t* W1h = Al + NN * NN;
    ushort_t* W2h = W1h + CIN * CH;    // total 180224 B

    const int E  = in_sizes[1] / 2;
    const int Bn = in_sizes[0] / (NN * CIN);

    prep_all<<<65, 256, 0, stream>>>(ei, E, W1, W2, Ah, Al, W1h, W2h);
    fused_all<<<Bn / 2, 256, 0, stream>>>(x, W1h, Ah, Al, W2h,
                                          b1, b2, fcW, fcb, outp);
}

// Round 19
// 79.521 us; speedup vs baseline: 1.5636x; 1.5636x over previous
//
#include <hip/hip_runtime.h>
#include <cstddef>

// B=2048, N=64, C_IN=512, C_H=128, NUM_CLASSES=2, E=1024
#define NN   64
#define CIN  512
#define CH   128

typedef unsigned short ushort_t;
typedef __attribute__((ext_vector_type(8))) short bf16x8;
typedef __attribute__((ext_vector_type(4))) short bf16x4;
typedef __attribute__((ext_vector_type(4))) float f32x4;

__device__ __forceinline__ ushort_t f2bf(float f) {          // RN-even fp32->bf16
    union { float f; unsigned u; } v; v.f = f;
    unsigned r = v.u + 0x7fffu + ((v.u >> 16) & 1u);
    return (ushort_t)(r >> 16);
}
__device__ __forceinline__ float bf2f(ushort_t b) {
    union { unsigned u; float f; } v; v.u = ((unsigned)b) << 16;
    return v.f;
}

// ---------------------------------------------------------------------------
// Kernel 1: block 0 builds normalized adjacency A (hi/lo bf16); blocks 1..64
// transpose + bf16 W1 (hi only) and W2 (hi only).
// ---------------------------------------------------------------------------
__global__ __launch_bounds__(256) void prep_all(const int* __restrict__ ei, int E,
                                                const float* __restrict__ W1,
                                                const float* __restrict__ W2,
                                                ushort_t* __restrict__ Ah, ushort_t* __restrict__ Al,
                                                ushort_t* __restrict__ W1h,
                                                ushort_t* __restrict__ W2h) {
    const int t = threadIdx.x;
    if (blockIdx.x == 0) {
        __shared__ float sdeg[NN];
        __shared__ float snorm[NN];
        __shared__ float sA[NN * NN];
        if (t < NN) sdeg[t] = 0.f;
        for (int i = t; i < NN * NN; i += 256) sA[i] = 0.f;
        __syncthreads();
        for (int e = t; e < E; e += 256) atomicAdd(&sdeg[ei[E + e]], 1.0f);
        __syncthreads();
        if (t < NN) snorm[t] = rsqrtf(sdeg[t] + 1.0f);
        __syncthreads();
        for (int e = t; e < E; e += 256) {
            int s = ei[e], d = ei[E + e];
            atomicAdd(&sA[d * NN + s], snorm[s] * snorm[d]);
        }
        if (t < NN) atomicAdd(&sA[t * NN + t], snorm[t] * snorm[t]);
        __syncthreads();
        for (int i = t; i < NN * NN; i += 256) {
            float a = sA[i];
            ushort_t h = f2bf(a);
            Ah[i] = h;
            Al[i] = f2bf(a - bf2f(h));
        }
    } else {
        const int idx = (blockIdx.x - 1) * 256 + t;
        const int stride = 64 * 256;
        for (int i = idx; i < CIN * CH; i += stride) {
            int k = i / CH, c = i % CH;
            W1h[c * CIN + k] = f2bf(W1[i]);          // hi only
        }
        for (int i = idx; i < CH * CH; i += stride) {
            int k = i / CH, c = i % CH;
            W2h[c * CH + k] = f2bf(W2[i]);           // hi only
        }
    }
}

// issue X loads for global chunk KC into named register set XR
#define ISSUE_X(XR, KC)                                                       \
{                                                                             \
    _Pragma("unroll")                                                         \
    for (int rf = 0; rf < 2; ++rf) {                                          \
        const float* xp = xp0 + rf * 16 * CIN + (KC) * 64;                    \
        XR[rf][0][0] = *reinterpret_cast<const float4*>(xp);                  \
        XR[rf][0][1] = *reinterpret_cast<const float4*>(xp + 4);              \
        XR[rf][1][0] = *reinterpret_cast<const float4*>(xp + 32);             \
        XR[rf][1][1] = *reinterpret_cast<const float4*>(xp + 36);             \
    }                                                                         \
}

// convert named set XR (loaded ~2 chunks ago) and MFMA against resident W
// at local chunk KCL (0..3 within the phase)
#define COMPUTE_CHUNK(XR, KCL)                                                \
{                                                                             \
    bf16x8 xh[2][2];                                                          \
    _Pragma("unroll")                                                         \
    for (int rf = 0; rf < 2; ++rf)                                            \
        _Pragma("unroll")                                                     \
        for (int ks = 0; ks < 2; ++ks) {                                      \
            const float xv[8] = {XR[rf][ks][0].x, XR[rf][ks][0].y,            \
                                 XR[rf][ks][0].z, XR[rf][ks][0].w,            \
                                 XR[rf][ks][1].x, XR[rf][ks][1].y,            \
                                 XR[rf][ks][1].z, XR[rf][ks][1].w};           \
            _Pragma("unroll")                                                 \
            for (int j = 0; j < 8; ++j)                                       \
                xh[rf][ks][j] = (short)f2bf(xv[j]);                           \
        }                                                                     \
    _Pragma("unroll")                                                         \
    for (int ks = 0; ks < 2; ++ks) {                                          \
        _Pragma("unroll")                                                     \
        for (int ct = 0; ct < 8; ++ct) {                                      \
            const int c = ct * 16 + lr;                                       \
            const int gk = (KCL) * 8 + (((ks << 2) | lk) ^ (c & 7));          \
            bf16x8 wh = *reinterpret_cast<const bf16x8*>(&lds[c * 256 + gk * 8]); \
            _Pragma("unroll")                                                 \
            for (int rf = 0; rf < 2; ++rf)                                    \
                acc[rf][ct] = __builtin_amdgcn_mfma_f32_16x16x32_bf16(xh[rf][ks], wh, acc[rf][ct], 0, 0, 0); \
        }                                                                     \
    }                                                                         \
}

// ---------------------------------------------------------------------------
// Kernel 2: FULLY FUSED — R19 = R17 (resident-W, barrier-free chunks) +
// 2-DEEP X prefetch (xrA/xrB): chunk k issues its set for chunk k+2, so
// every X load has ~800-1000 cyc of cover (~HBM latency) with no vmcnt
// drain in between (R12's 2-deep had per-chunk drains; R17 was 1-deep;
// R18's 4-deep blew the register budget -> VGPR 116 crush).
// Register budget: acc 64 + X sets 64 + staging transients (~unroll 4) ->
// ~190 VGPR, inside the proven-working band.
// Structure otherwise identical to R17/R16.
// ---------------------------------------------------------------------------
__global__ __launch_bounds__(256, 2) void fused_all(
    const float* __restrict__ x,
    const ushort_t* __restrict__ W1h,
    const ushort_t* __restrict__ Ah, const ushort_t* __restrict__ Al,
    const ushort_t* __restrict__ W2h,
    const float* __restrict__ b1, const float* __restrict__ b2,
    const float* __restrict__ fcW, const float* __restrict__ fcb,
    float* __restrict__ out)
{
    __shared__ ushort_t lds[32768];     // 65536 B
    __shared__ float sred[16];

    const int t   = threadIdx.x;
    const int l   = t & 63;
    const int w   = t >> 6;             // 0..3
    const int lr  = l & 15;
    const int lk  = l >> 4;
    const int lr7 = lr & 7;
    const size_t rbase = (size_t)blockIdx.x * 128;

    const float* xp0 = x + (rbase + w * 32 + lr) * CIN + lk * 8;
    float4 xrA[2][2][2], xrB[2][2][2];  // 2-deep X prefetch (named sets)

    // ---- prologue: issue X chunks 0 (A), 1 (B) ----
    ISSUE_X(xrA, 0);
    ISSUE_X(xrB, 1);

    f32x4 acc[2][8];
    #pragma unroll
    for (int rf = 0; rf < 2; ++rf)
        #pragma unroll
        for (int ct = 0; ct < 8; ++ct)
            #pragma unroll
            for (int i = 0; i < 4; ++i) acc[rf][ct][i] = 0.f;

    // ---- gemm1 phase 0: stage W K-half 0; chunks 0..3 barrier-free,
    //      each re-issuing its set for chunk+2 ----
    #pragma unroll 4
    for (int u = 0; u < 16; ++u) {
        int idx = u * 256 + t;
        int c = idx >> 5, g = idx & 31;
        int gs = (g & ~7) | ((g & 7) ^ (c & 7));
        *reinterpret_cast<bf16x8*>(&lds[c * 256 + gs * 8]) =
            *reinterpret_cast<const bf16x8*>(W1h + (size_t)c * CIN + g * 8);
    }
    __syncthreads();

    COMPUTE_CHUNK(xrA, 0); ISSUE_X(xrA, 2);
    COMPUTE_CHUNK(xrB, 1); ISSUE_X(xrB, 3);
    COMPUTE_CHUNK(xrA, 2); ISSUE_X(xrA, 4);
    COMPUTE_CHUNK(xrB, 3); ISSUE_X(xrB, 5);

    // ---- gemm1 phase 1: stage W K-half 1; chunks 4..7 ----
    __syncthreads();
    #pragma unroll 4
    for (int u = 0; u < 16; ++u) {
        int idx = u * 256 + t;
        int c = idx >> 5, g = idx & 31;
        int gs = (g & ~7) | ((g & 7) ^ (c & 7));
        *reinterpret_cast<bf16x8*>(&lds[c * 256 + gs * 8]) =
            *reinterpret_cast<const bf16x8*>(W1h + (size_t)c * CIN + 256 + g * 8);
    }
    __syncthreads();

    COMPUTE_CHUNK(xrA, 0); ISSUE_X(xrA, 6);
    COMPUTE_CHUNK(xrB, 1); ISSUE_X(xrB, 7);
    COMPUTE_CHUNK(xrA, 2);
    COMPUTE_CHUNK(xrB, 3);

    __syncthreads();                    // gemm1 done; W region now dead

    // ================= tail (in-block) =================
    // sYt: batch qb at lds[qb*8192], tile [c(128)][n(64)] swizzled.
    // sH1: batch qb at lds[16384 + qb*8192], tile [n(64)][c(128)] swizzled.

    // ---- Y1 (registers) -> sYt, bf16 ----
    #pragma unroll
    for (int rf = 0; rf < 2; ++rf) {
        const int grow = w * 32 + rf * 16 + lk * 4;
        const int qb   = grow >> 6;
        const int n0   = grow & 63;
        const int gn   = n0 >> 3, noff = n0 & 7;
        #pragma unroll
        for (int ct = 0; ct < 8; ++ct) {
            const int c = ct * 16 + lr;
            bf16x4 yv;
            #pragma unroll
            for (int r = 0; r < 4; ++r) yv[r] = (short)f2bf(acc[rf][ct][r]);
            *reinterpret_cast<bf16x4*>(&lds[qb * 8192 + c * 64 + ((gn ^ lr7) << 3) + noff]) = yv;
        }
    }
    __syncthreads();

    const int q = w >> 1;               // batch within block
    const int h = w & 1;                // 32-row half
    ushort_t* sYtq = &lds[q * 8192];
    ushort_t* sH1q = &lds[16384 + q * 8192];

    // ---- agg1: H1 = relu(A @ Y1 + b1) -> sH1 ----
    bf16x8 ahf[2][2], alf[2][2];        // [rf][ks]
    #pragma unroll
    for (int rf = 0; rf < 2; ++rf)
        #pragma unroll
        for (int ks = 0; ks < 2; ++ks) {
            const int nrow = h * 32 + rf * 16 + lr;
            const int ko = ks * 32 + lk * 8;
            ahf[rf][ks] = *reinterpret_cast<const bf16x8*>(Ah + nrow * NN + ko);
            alf[rf][ks] = *reinterpret_cast<const bf16x8*>(Al + nrow * NN + ko);
        }
    {
        f32x4 hacc[2][8];
        #pragma unroll
        for (int rf = 0; rf < 2; ++rf)
            #pragma unroll
            for (int ct = 0; ct < 8; ++ct)
                #pragma unroll
                for (int i = 0; i < 4; ++i) hacc[rf][ct][i] = 0.f;
        #pragma unroll
        for (int ks = 0; ks < 2; ++ks) {
            const int swz = (((ks << 2) | lk) ^ lr7) << 3;
            #pragma unroll
            for (int ct = 0; ct < 8; ++ct) {
                const int c = ct * 16 + lr;
                bf16x8 y = *reinterpret_cast<const bf16x8*>(&sYtq[c * 64 + swz]);
                #pragma unroll
                for (int rf = 0; rf < 2; ++rf) {
                    hacc[rf][ct] = __builtin_amdgcn_mfma_f32_16x16x32_bf16(ahf[rf][ks], y, hacc[rf][ct], 0, 0, 0);
                    hacc[rf][ct] = __builtin_amdgcn_mfma_f32_16x16x32_bf16(alf[rf][ks], y, hacc[rf][ct], 0, 0, 0);
                }
            }
        }
        #pragma unroll
        for (int rf = 0; rf < 2; ++rf)
            #pragma unroll
            for (int ct = 0; ct < 8; ++ct) {
                const int c = ct * 16 + lr;
                const int gc = c >> 3;
                const float bias = b1[c];
                #pragma unroll
                for (int r = 0; r < 4; ++r) {
                    const int n = h * 32 + rf * 16 + lk * 4 + r;
                    float v = fmaxf(hacc[rf][ct][r] + bias, 0.f);
                    sH1q[n * 128 + ((gc ^ (n & 7)) << 3) + (c & 7)] = f2bf(v);
                }
            }
    }
    __syncthreads();

    // ---- stage W2h into LDS (sYt region; Y1 dead, Y2 not yet written) ----
    #pragma unroll
    for (int u = 0; u < 8; ++u) {
        int idx = u * 256 + t;          // granule id 0..2047
        int c = idx >> 4, g = idx & 15;
        *reinterpret_cast<bf16x8*>(&lds[c * 128 + ((g ^ (c & 7)) << 3)]) =
            *reinterpret_cast<const bf16x8*>(W2h + (size_t)c * CH + g * 8);
    }
    __syncthreads();

    // ---- gemm2: Y2 = H1 @ W2h (1-pass), W2 from LDS ----
    f32x4 acc2[2][8];
    #pragma unroll
    for (int rf = 0; rf < 2; ++rf)
        #pragma unroll
        for (int ct = 0; ct < 8; ++ct)
            #pragma unroll
            for (int i = 0; i < 4; ++i) acc2[rf][ct][i] = 0.f;
    {
        bf16x8 hf[2][4];                // [rf][ks], K=128
        #pragma unroll
        for (int rf = 0; rf < 2; ++rf) {
            const int n = h * 32 + rf * 16 + lr;
            #pragma unroll
            for (int ks = 0; ks < 4; ++ks) {
                const int gh = ((ks << 2) | lk) ^ (n & 7);
                hf[rf][ks] = *reinterpret_cast<const bf16x8*>(&sH1q[n * 128 + (gh << 3)]);
            }
        }
        #pragma unroll
        for (int ct = 0; ct < 8; ++ct) {
            const int c = ct * 16 + lr;
            #pragma unroll
            for (int ks = 0; ks < 4; ++ks) {
                const int gw = ((ks << 2) | lk) ^ (c & 7);
                bf16x8 w2 = *reinterpret_cast<const bf16x8*>(&lds[c * 128 + (gw << 3)]);
                #pragma unroll
                for (int rf = 0; rf < 2; ++rf)
                    acc2[rf][ct] = __builtin_amdgcn_mfma_f32_16x16x32_bf16(hf[rf][ks], w2, acc2[rf][ct], 0, 0, 0);
            }
        }
    }
    __syncthreads();                    // all W2h reads done before Y2 overwrite

    // Y2 -> sYt
    #pragma unroll
    for (int rf = 0; rf < 2; ++rf) {
        const int n0 = h * 32 + rf * 16 + lk * 4;
        const int gn = n0 >> 3, noff = n0 & 7;
        #pragma unroll
        for (int ct = 0; ct < 8; ++ct) {
            const int c = ct * 16 + lr;
            bf16x4 yv;
            #pragma unroll
            for (int r = 0; r < 4; ++r) yv[r] = (short)f2bf(acc2[rf][ct][r]);
            *reinterpret_cast<bf16x4*>(&sYtq[c * 64 + ((gn ^ lr7) << 3) + noff]) = yv;
        }
    }
    __syncthreads();

    // ---- agg2 + bias + relu + FC ----
    float p0 = 0.f, p1 = 0.f;
    {
        f32x4 h2[2][8];
        #pragma unroll
        for (int rf = 0; rf < 2; ++rf)
            #pragma unroll
            for (int ct = 0; ct < 8; ++ct)
                #pragma unroll
                for (int i = 0; i < 4; ++i) h2[rf][ct][i] = 0.f;
        #pragma unroll
        for (int ks = 0; ks < 2; ++ks) {
            const int swz = (((ks << 2) | lk) ^ lr7) << 3;
            #pragma unroll
            for (int ct = 0; ct < 8; ++ct) {
                const int c = ct * 16 + lr;
                bf16x8 y = *reinterpret_cast<const bf16x8*>(&sYtq[c * 64 + swz]);
                #pragma unroll
                for (int rf = 0; rf < 2; ++rf) {
                    h2[rf][ct] = __builtin_amdgcn_mfma_f32_16x16x32_bf16(ahf[rf][ks], y, h2[rf][ct], 0, 0, 0);
                    h2[rf][ct] = __builtin_amdgcn_mfma_f32_16x16x32_bf16(alf[rf][ks], y, h2[rf][ct], 0, 0, 0);
                }
            }
        }
        #pragma unroll
        for (int rf = 0; rf < 2; ++rf)
            #pragma unroll
            for (int ct = 0; ct < 8; ++ct) {
                const int c = ct * 16 + lr;
                const float bias = b2[c];
                #pragma unroll
                for (int r = 0; r < 4; ++r) {
                    const int n = h * 32 + rf * 16 + lk * 4 + r;
                    float v = fmaxf(h2[rf][ct][r] + bias, 0.f);
                    const float2 fw = *reinterpret_cast<const float2*>(fcW + ((size_t)(n * CH + c)) * 2);
                    p0 = fmaf(v, fw.x, p0);
                    p1 = fmaf(v, fw.y, p1);
                }
            }
    }
    #pragma unroll
    for (int off = 32; off > 0; off >>= 1) {
        p0 += __shfl_down(p0, off);
        p1 += __shfl_down(p1, off);
    }
    if (l == 0) { sred[w * 2] = p0; sred[w * 2 + 1] = p1; }
    __syncthreads();
    if (t == 0) {
        const size_t bA = (size_t)blockIdx.x * 2;
        out[bA * 2 + 0]       = sred[0] + sred[2] + fcb[0];
        out[bA * 2 + 1]       = sred[1] + sred[3] + fcb[1];
        out[(bA + 1) * 2 + 0] = sred[4] + sred[6] + fcb[0];
        out[(bA + 1) * 2 + 1] = sred[5] + sred[7] + fcb[1];
    }
}

// ---------------------------------------------------------------------------
extern "C" void kernel_launch(void* const* d_in, const int* in_sizes, int n_in,
                              void* d_out, int out_size, void* d_ws, size_t ws_size,
                              hipStream_t stream) {
    const float* x   = (const float*)d_in[0];
    const int*   ei  = (const int*)d_in[1];
    const float* W1  = (const float*)d_in[2];
    const float* b1  = (const float*)d_in[3];
    const float* W2  = (const float*)d_in[4];
    const float* b2  = (const float*)d_in[5];
    const float* fcW = (const float*)d_in[6];
    const float* fcb = (const float*)d_in[7];
    float* outp = (float*)d_out;

    // ws layout (bf16 elems): Ah,Al [64*64]; W1h [128*512]; W2h [128*128]
    ushort_t* Ah  = (ushort_t*)d_ws;
    ushort_t* Al  = Ah + NN * NN;
    ushort_t* W1h = Al + NN * NN;
    ushort_t* W2h = W1h + CIN * CH;    // total 180224 B

    const int E  = in_sizes[1] / 2;
    const int Bn = in_sizes[0] / (NN * CIN);

    prep_all<<<65, 256, 0, stream>>>(ei, E, W1, W2, Ah, Al, W1h, W2h);
    fused_all<<<Bn / 2, 256, 0, stream>>>(x, W1h, Ah, Al, W2h,
                                          b1, b2, fcW, fcb, outp);
}

// Round 20
// 75.635 us; speedup vs baseline: 1.6440x; 1.0514x over previous
//
#include <hip/hip_runtime.h>
#include <cstddef>

// B=2048, N=64, C_IN=512, C_H=128, NUM_CLASSES=2, E=1024
#define NN   64
#define CIN  512
#define CH   128

typedef unsigned short ushort_t;
typedef __attribute__((ext_vector_type(8))) short bf16x8;
typedef __attribute__((ext_vector_type(4))) short bf16x4;
typedef __attribute__((ext_vector_type(4))) float f32x4;

__device__ __forceinline__ ushort_t f2bf(float f) {          // RN-even fp32->bf16
    union { float f; unsigned u; } v; v.f = f;
    unsigned r = v.u + 0x7fffu + ((v.u >> 16) & 1u);
    return (ushort_t)(r >> 16);
}
__device__ __forceinline__ float bf2f(ushort_t b) {
    union { unsigned u; float f; } v; v.u = ((unsigned)b) << 16;
    return v.f;
}

// ---------------------------------------------------------------------------
// Kernel 1: block 0 builds normalized adjacency A (hi/lo bf16); blocks 1..64
// transpose + bf16 W1 (hi only) and W2 (hi only).
// ---------------------------------------------------------------------------
__global__ __launch_bounds__(256) void prep_all(const int* __restrict__ ei, int E,
                                                const float* __restrict__ W1,
                                                const float* __restrict__ W2,
                                                ushort_t* __restrict__ Ah, ushort_t* __restrict__ Al,
                                                ushort_t* __restrict__ W1h,
                                                ushort_t* __restrict__ W2h) {
    const int t = threadIdx.x;
    if (blockIdx.x == 0) {
        __shared__ float sdeg[NN];
        __shared__ float snorm[NN];
        __shared__ float sA[NN * NN];
        if (t < NN) sdeg[t] = 0.f;
        for (int i = t; i < NN * NN; i += 256) sA[i] = 0.f;
        __syncthreads();
        for (int e = t; e < E; e += 256) atomicAdd(&sdeg[ei[E + e]], 1.0f);
        __syncthreads();
        if (t < NN) snorm[t] = rsqrtf(sdeg[t] + 1.0f);
        __syncthreads();
        for (int e = t; e < E; e += 256) {
            int s = ei[e], d = ei[E + e];
            atomicAdd(&sA[d * NN + s], snorm[s] * snorm[d]);
        }
        if (t < NN) atomicAdd(&sA[t * NN + t], snorm[t] * snorm[t]);
        __syncthreads();
        for (int i = t; i < NN * NN; i += 256) {
            float a = sA[i];
            ushort_t h = f2bf(a);
            Ah[i] = h;
            Al[i] = f2bf(a - bf2f(h));
        }
    } else {
        const int idx = (blockIdx.x - 1) * 256 + t;
        const int stride = 64 * 256;
        for (int i = idx; i < CIN * CH; i += stride) {
            int k = i / CH, c = i % CH;
            W1h[c * CIN + k] = f2bf(W1[i]);          // hi only
        }
        for (int i = idx; i < CH * CH; i += stride) {
            int k = i / CH, c = i % CH;
            W2h[c * CH + k] = f2bf(W2[i]);           // hi only
        }
    }
}

// ---------------------------------------------------------------------------
// Kernel 2: FULLY FUSED — best variant (R16): R13 structure with X-HI ONLY
// gemm1 (1-pass). 256 thr = 4 waves; wave w owns rows [w*32,+32) (rf=2x16)
// x all 128 cols (ct=8); block = 2 batches; W1 LDS dbuf (reg-staged,
// swizzled); 1-deep X register prefetch; tail = agg1 (A 2-pass) -> gemm2
// (W2h from LDS, 1-pass) -> agg2 -> FC.
// LDS 64KB -> 2 blocks/CU. 16B-granule XOR swizzle: granule g of row r at
// slot g^(r&7) (both-sides, bijective).
// Measured: 76.1 µs, absmax 1.953e-3 (threshold 6.05e-3). Rounds 12-19
// falsified every structural lever around this design (prefetch depth,
// barrier cadence/removal, occupancy, compute halving) — delivery-bound on
// the mandatory 268 MB fp32 X read at ~4.3-4.5 TB/s effective.
// ---------------------------------------------------------------------------
__global__ __launch_bounds__(256, 2) void fused_all(
    const float* __restrict__ x,
    const ushort_t* __restrict__ W1h,
    const ushort_t* __restrict__ Ah, const ushort_t* __restrict__ Al,
    const ushort_t* __restrict__ W2h,
    const float* __restrict__ b1, const float* __restrict__ b2,
    const float* __restrict__ fcW, const float* __restrict__ fcb,
    float* __restrict__ out)
{
    __shared__ ushort_t lds[32768];     // 65536 B
    __shared__ float sred[16];

    const int t   = threadIdx.x;
    const int l   = t & 63;
    const int w   = t >> 6;             // 0..3
    const int lr  = l & 15;
    const int lk  = l >> 4;
    const int lr7 = lr & 7;
    const size_t rbase = (size_t)blockIdx.x * 128;

    const float* xp0 = x + (rbase + w * 32 + lr) * CIN + lk * 8;
    bf16x8 wreg[4];                     // W1 chunk staging regs
    float4 xraw[2][2][2];               // [rf][ks][half] next-chunk X

    // ---- prologue: issue X chunk 0, stage W1 chunk 0 (swizzled) ----
    #pragma unroll
    for (int rf = 0; rf < 2; ++rf) {
        const float* xp = xp0 + rf * 16 * CIN;
        xraw[rf][0][0] = *reinterpret_cast<const float4*>(xp);
        xraw[rf][0][1] = *reinterpret_cast<const float4*>(xp + 4);
        xraw[rf][1][0] = *reinterpret_cast<const float4*>(xp + 32);
        xraw[rf][1][1] = *reinterpret_cast<const float4*>(xp + 36);
    }
    #pragma unroll
    for (int u = 0; u < 4; ++u) {
        int q = u * 256 + t, c = q >> 3, g = q & 7;
        wreg[u] = *reinterpret_cast<const bf16x8*>(W1h + (size_t)c * CIN + g * 8);
    }
    #pragma unroll
    for (int u = 0; u < 4; ++u) {
        int q = u * 256 + t, c = q >> 3, g = q & 7;
        *reinterpret_cast<bf16x8*>(&lds[c * 64 + ((g ^ (c & 7)) << 3)]) = wreg[u];
    }
    __syncthreads();

    f32x4 acc[2][8];
    #pragma unroll
    for (int rf = 0; rf < 2; ++rf)
        #pragma unroll
        for (int ct = 0; ct < 8; ++ct)
            #pragma unroll
            for (int i = 0; i < 4; ++i) acc[rf][ct][i] = 0.f;

    for (int kc = 0; kc < 8; ++kc) {
        const ushort_t* sWh = &lds[(kc & 1) * 8192];

        // convert previously-loaded X (latency covered) -> bf16 hi ONLY
        bf16x8 xh[2][2];
        #pragma unroll
        for (int rf = 0; rf < 2; ++rf)
            #pragma unroll
            for (int ks = 0; ks < 2; ++ks) {
                const float xv[8] = {xraw[rf][ks][0].x, xraw[rf][ks][0].y,
                                     xraw[rf][ks][0].z, xraw[rf][ks][0].w,
                                     xraw[rf][ks][1].x, xraw[rf][ks][1].y,
                                     xraw[rf][ks][1].z, xraw[rf][ks][1].w};
                #pragma unroll
                for (int j = 0; j < 8; ++j)
                    xh[rf][ks][j] = (short)f2bf(xv[j]);
            }
        // issue next-chunk X + W1 loads (covered by this chunk's compute)
        if (kc < 7) {
            #pragma unroll
            for (int rf = 0; rf < 2; ++rf) {
                const float* xp = xp0 + rf * 16 * CIN + (kc + 1) * 64;
                xraw[rf][0][0] = *reinterpret_cast<const float4*>(xp);
                xraw[rf][0][1] = *reinterpret_cast<const float4*>(xp + 4);
                xraw[rf][1][0] = *reinterpret_cast<const float4*>(xp + 32);
                xraw[rf][1][1] = *reinterpret_cast<const float4*>(xp + 36);
            }
            #pragma unroll
            for (int u = 0; u < 4; ++u) {
                int q = u * 256 + t, c = q >> 3, g = q & 7;
                wreg[u] = *reinterpret_cast<const bf16x8*>(W1h + (size_t)c * CIN + (kc + 1) * 64 + g * 8);
            }
        }
        // compute chunk kc: 1-pass (xh*wh)
        #pragma unroll
        for (int ks = 0; ks < 2; ++ks) {
            const int swz = (((ks << 2) | lk) ^ lr7) << 3;
            #pragma unroll
            for (int ct = 0; ct < 8; ++ct) {
                const int c = ct * 16 + lr;
                bf16x8 wh = *reinterpret_cast<const bf16x8*>(&sWh[c * 64 + swz]);
                #pragma unroll
                for (int rf = 0; rf < 2; ++rf)
                    acc[rf][ct] = __builtin_amdgcn_mfma_f32_16x16x32_bf16(xh[rf][ks], wh, acc[rf][ct], 0, 0, 0);
            }
        }
        if (kc < 7) {
            const int nb = ((kc & 1) ^ 1) * 8192;
            #pragma unroll
            for (int u = 0; u < 4; ++u) {
                int q = u * 256 + t, c = q >> 3, g = q & 7;
                *reinterpret_cast<bf16x8*>(&lds[nb + c * 64 + ((g ^ (c & 7)) << 3)]) = wreg[u];
            }
        }
        __syncthreads();
    }

    // ================= tail (in-block) =================
    // sYt: batch qb at lds[qb*8192], tile [c(128)][n(64)] swizzled.
    // sH1: batch qb at lds[16384 + qb*8192], tile [n(64)][c(128)] swizzled.

    // ---- Y1 (registers) -> sYt, bf16 ----
    #pragma unroll
    for (int rf = 0; rf < 2; ++rf) {
        const int grow = w * 32 + rf * 16 + lk * 4;
        const int qb   = grow >> 6;
        const int n0   = grow & 63;
        const int gn   = n0 >> 3, noff = n0 & 7;
        #pragma unroll
        for (int ct = 0; ct < 8; ++ct) {
            const int c = ct * 16 + lr;
            bf16x4 yv;
            #pragma unroll
            for (int r = 0; r < 4; ++r) yv[r] = (short)f2bf(acc[rf][ct][r]);
            *reinterpret_cast<bf16x4*>(&lds[qb * 8192 + c * 64 + ((gn ^ lr7) << 3) + noff]) = yv;
        }
    }
    __syncthreads();

    const int q = w >> 1;               // batch within block
    const int h = w & 1;                // 32-row half
    ushort_t* sYtq = &lds[q * 8192];
    ushort_t* sH1q = &lds[16384 + q * 8192];

    // ---- agg1: H1 = relu(A @ Y1 + b1) -> sH1 ----
    bf16x8 ahf[2][2], alf[2][2];        // [rf][ks]
    #pragma unroll
    for (int rf = 0; rf < 2; ++rf)
        #pragma unroll
        for (int ks = 0; ks < 2; ++ks) {
            const int nrow = h * 32 + rf * 16 + lr;
            const int ko = ks * 32 + lk * 8;
            ahf[rf][ks] = *reinterpret_cast<const bf16x8*>(Ah + nrow * NN + ko);
            alf[rf][ks] = *reinterpret_cast<const bf16x8*>(Al + nrow * NN + ko);
        }
    {
        f32x4 hacc[2][8];
        #pragma unroll
        for (int rf = 0; rf < 2; ++rf)
            #pragma unroll
            for (int ct = 0; ct < 8; ++ct)
                #pragma unroll
                for (int i = 0; i < 4; ++i) hacc[rf][ct][i] = 0.f;
        #pragma unroll
        for (int ks = 0; ks < 2; ++ks) {
            const int swz = (((ks << 2) | lk) ^ lr7) << 3;
            #pragma unroll
            for (int ct = 0; ct < 8; ++ct) {
                const int c = ct * 16 + lr;
                bf16x8 y = *reinterpret_cast<const bf16x8*>(&sYtq[c * 64 + swz]);
                #pragma unroll
                for (int rf = 0; rf < 2; ++rf) {
                    hacc[rf][ct] = __builtin_amdgcn_mfma_f32_16x16x32_bf16(ahf[rf][ks], y, hacc[rf][ct], 0, 0, 0);
                    hacc[rf][ct] = __builtin_amdgcn_mfma_f32_16x16x32_bf16(alf[rf][ks], y, hacc[rf][ct], 0, 0, 0);
                }
            }
        }
        #pragma unroll
        for (int rf = 0; rf < 2; ++rf)
            #pragma unroll
            for (int ct = 0; ct < 8; ++ct) {
                const int c = ct * 16 + lr;
                const int gc = c >> 3;
                const float bias = b1[c];
                #pragma unroll
                for (int r = 0; r < 4; ++r) {
                    const int n = h * 32 + rf * 16 + lk * 4 + r;
                    float v = fmaxf(hacc[rf][ct][r] + bias, 0.f);
                    sH1q[n * 128 + ((gc ^ (n & 7)) << 3) + (c & 7)] = f2bf(v);
                }
            }
    }
    __syncthreads();

    // ---- stage W2h into LDS (sYt region; Y1 dead, Y2 not yet written) ----
    #pragma unroll
    for (int u = 0; u < 8; ++u) {
        int idx = u * 256 + t;          // granule id 0..2047
        int c = idx >> 4, g = idx & 15;
        *reinterpret_cast<bf16x8*>(&lds[c * 128 + ((g ^ (c & 7)) << 3)]) =
            *reinterpret_cast<const bf16x8*>(W2h + (size_t)c * CH + g * 8);
    }
    __syncthreads();

    // ---- gemm2: Y2 = H1 @ W2h (1-pass), W2 from LDS ----
    f32x4 acc2[2][8];
    #pragma unroll
    for (int rf = 0; rf < 2; ++rf)
        #pragma unroll
        for (int ct = 0; ct < 8; ++ct)
            #pragma unroll
            for (int i = 0; i < 4; ++i) acc2[rf][ct][i] = 0.f;
    {
        bf16x8 hf[2][4];                // [rf][ks], K=128
        #pragma unroll
        for (int rf = 0; rf < 2; ++rf) {
            const int n = h * 32 + rf * 16 + lr;
            #pragma unroll
            for (int ks = 0; ks < 4; ++ks) {
                const int gh = ((ks << 2) | lk) ^ (n & 7);
                hf[rf][ks] = *reinterpret_cast<const bf16x8*>(&sH1q[n * 128 + (gh << 3)]);
            }
        }
        #pragma unroll
        for (int ct = 0; ct < 8; ++ct) {
            const int c = ct * 16 + lr;
            #pragma unroll
            for (int ks = 0; ks < 4; ++ks) {
                const int gw = ((ks << 2) | lk) ^ (c & 7);
                bf16x8 w2 = *reinterpret_cast<const bf16x8*>(&lds[c * 128 + (gw << 3)]);
                #pragma unroll
                for (int rf = 0; rf < 2; ++rf)
                    acc2[rf][ct] = __builtin_amdgcn_mfma_f32_16x16x32_bf16(hf[rf][ks], w2, acc2[rf][ct], 0, 0, 0);
            }
        }
    }
    __syncthreads();                    // all W2h reads done before Y2 overwrite

    // Y2 -> sYt
    #pragma unroll
    for (int rf = 0; rf < 2; ++rf) {
        const int n0 = h * 32 + rf * 16 + lk * 4;
        const int gn = n0 >> 3, noff = n0 & 7;
        #pragma unroll
        for (int ct = 0; ct < 8; ++ct) {
            const int c = ct * 16 + lr;
            bf16x4 yv;
            #pragma unroll
            for (int r = 0; r < 4; ++r) yv[r] = (short)f2bf(acc2[rf][ct][r]);
            *reinterpret_cast<bf16x4*>(&sYtq[c * 64 + ((gn ^ lr7) << 3) + noff]) = yv;
        }
    }
    __syncthreads();

    // ---- agg2 + bias + relu + FC ----
    float p0 = 0.f, p1 = 0.f;
    {
        f32x4 h2[2][8];
        #pragma unroll
        for (int rf = 0; rf < 2; ++rf)
            #pragma unroll
            for (int ct = 0; ct < 8; ++ct)
                #pragma unroll
                for (int i = 0; i < 4; ++i) h2[rf][ct][i] = 0.f;
        #pragma unroll
        for (int ks = 0; ks < 2; ++ks) {
            const int swz = (((ks << 2) | lk) ^ lr7) << 3;
            #pragma unroll
            for (int ct = 0; ct < 8; ++ct) {
                const int c = ct * 16 + lr;
                bf16x8 y = *reinterpret_cast<const bf16x8*>(&sYtq[c * 64 + swz]);
                #pragma unroll
                for (int rf = 0; rf < 2; ++rf) {
                    h2[rf][ct] = __builtin_amdgcn_mfma_f32_16x16x32_bf16(ahf[rf][ks], y, h2[rf][ct], 0, 0, 0);
                    h2[rf][ct] = __builtin_amdgcn_mfma_f32_16x16x32_bf16(alf[rf][ks], y, h2[rf][ct], 0, 0, 0);
                }
            }
        }
        #pragma unroll
        for (int rf = 0; rf < 2; ++rf)
            #pragma unroll
            for (int ct = 0; ct < 8; ++ct) {
                const int c = ct * 16 + lr;
                const float bias = b2[c];
                #pragma unroll
                for (int r = 0; r < 4; ++r) {
                    const int n = h * 32 + rf * 16 + lk * 4 + r;
                    float v = fmaxf(h2[rf][ct][r] + bias, 0.f);
                    const float2 fw = *reinterpret_cast<const float2*>(fcW + ((size_t)(n * CH + c)) * 2);
                    p0 = fmaf(v, fw.x, p0);
                    p1 = fmaf(v, fw.y, p1);
                }
            }
    }
    #pragma unroll
    for (int off = 32; off > 0; off >>= 1) {
        p0 += __shfl_down(p0, off);
        p1 += __shfl_down(p1, off);
    }
    if (l == 0) { sred[w * 2] = p0; sred[w * 2 + 1] = p1; }
    __syncthreads();
    if (t == 0) {
        const size_t bA = (size_t)blockIdx.x * 2;
        out[bA * 2 + 0]       = sred[0] + sred[2] + fcb[0];
        out[bA * 2 + 1]       = sred[1] + sred[3] + fcb[1];
        out[(bA + 1) * 2 + 0] = sred[4] + sred[6] + fcb[0];
        out[(bA + 1) * 2 + 1] = sred[5] + sred[7] + fcb[1];
    }
}

// ---------------------------------------------------------------------------
extern "C" void kernel_launch(void* const* d_in, const int* in_sizes, int n_in,
                              void* d_out, int out_size, void* d_ws, size_t ws_size,
                              hipStream_t stream) {
    const float* x   = (const float*)d_in[0];
    const int*   ei  = (const int*)d_in[1];
    const float* W1  = (const float*)d_in[2];
    const float* b1  = (const float*)d_in[3];
    const float* W2  = (const float*)d_in[4];
    const float* b2  = (const float*)d_in[5];
    const float* fcW = (const float*)d_in[6];
    const float* fcb = (const float*)d_in[7];
    float* outp = (float*)d_out;

    // ws layout (bf16 elems): Ah,Al [64*64]; W1h [128*512]; W2h [128*128]
    ushort_t* Ah  = (ushort_t*)d_ws;
    ushort_t* Al  = Ah + NN * NN;
    ushort_t* W1h = Al + NN * NN;
    ushort_t* W2h = W1h + CIN * CH;    // total 180224 B

    const int E  = in_sizes[1] / 2;
    const int Bn = in_sizes[0] / (NN * CIN);

    prep_all<<<65, 256, 0, stream>>>(ei, E, W1, W2, Ah, Al, W1h, W2h);
    fused_all<<<Bn / 2, 256, 0, stream>>>(x, W1h, Ah, Al, W2h,
                                          b1, b2, fcW, fcb, outp);
}